// Round 1
// baseline (1096.822 us; speedup 1.0000x reference)
//
#include <hip/hip_runtime.h>

// Problem constants (match reference)
constexpr int N_ROWS = 131072;
constexpr int DIM    = 512;
constexpr int KP     = 512;   // number of prototypes
constexpr int BM     = 32;    // rows per block
constexpr int BK     = 16;    // K-dim chunk staged in LDS

// ---------------------------------------------------------------------------
// pnorm[k] = sum_d P[k][d]^2   (one 64-lane wave per prototype row)
// ---------------------------------------------------------------------------
__global__ void pnorm_kernel(const float* __restrict__ P, float* __restrict__ pn) {
    int k = blockIdx.x;
    int lane = threadIdx.x;  // 64 threads
    const float4* row = reinterpret_cast<const float4*>(P + (size_t)k * DIM);
    float s = 0.f;
#pragma unroll
    for (int i = 0; i < 2; ++i) {
        float4 v = row[lane + 64 * i];
        s += v.x * v.x + v.y * v.y + v.z * v.z + v.w * v.w;
    }
#pragma unroll
    for (int off = 32; off > 0; off >>= 1) s += __shfl_down(s, off);
    if (lane == 0) pn[k] = s;
}

// ---------------------------------------------------------------------------
// Main kernel: per block of 32 rows, compute dots vs all 512 prototypes,
// fused argmin + codebook gather + quantized write + loss partial sum.
// Thread layout: 256 threads = 4 waves. Wave w owns rows w*8..w*8+7.
// Lane pc owns prototypes pc*8..pc*8+7 (all waves cover all 512 protos).
// ---------------------------------------------------------------------------
__launch_bounds__(256, 4)
__global__ void vq_main(const float* __restrict__ X, const float* __restrict__ P,
                        const float* __restrict__ pn, float* __restrict__ out,
                        double* __restrict__ lsum_g) {
    __shared__ float Xs[BK][BM + 1];     // transposed: Xs[k][row]
    __shared__ float Ps[BK][KP + 4];     // transposed: Ps[k][proto]
    __shared__ int idx_s[BM];
    __shared__ double wsum[4];

    const int tid  = threadIdx.x;
    const int lane = tid & 63;
    const int wid  = tid >> 6;       // wave id = row-group
    const int pc8  = lane * 8;       // first prototype owned by this lane
    const int r0   = wid * 8;        // first row owned by this wave
    const int row0 = blockIdx.x * BM;

    float acc[8][8];
#pragma unroll
    for (int i = 0; i < 8; ++i)
#pragma unroll
        for (int j = 0; j < 8; ++j) acc[i][j] = 0.f;

    for (int ks = 0; ks < DIM; ks += BK) {
        __syncthreads();
        // stage X chunk (32 rows x 16 dims), transposed
        if (tid < 128) {
            int r = tid & 31;
            int f = tid >> 5;  // 0..3
            float4 v = *reinterpret_cast<const float4*>(
                X + (size_t)(row0 + r) * DIM + ks + 4 * f);
            Xs[4 * f + 0][r] = v.x;
            Xs[4 * f + 1][r] = v.y;
            Xs[4 * f + 2][r] = v.z;
            Xs[4 * f + 3][r] = v.w;
        }
        // stage P chunk (512 protos x 16 dims), transposed
#pragma unroll
        for (int it = 0; it < 8; ++it) {
            int q = it * 256 + tid;     // 0..2047
            int c = q >> 2;             // proto row
            int f = q & 3;              // which float4 of the 16-dim chunk
            float4 v = *reinterpret_cast<const float4*>(
                P + (size_t)c * DIM + ks + 4 * f);
            Ps[4 * f + 0][c] = v.x;
            Ps[4 * f + 1][c] = v.y;
            Ps[4 * f + 2][c] = v.z;
            Ps[4 * f + 3][c] = v.w;
        }
        __syncthreads();
#pragma unroll
        for (int k = 0; k < BK; ++k) {
            float xv[8];
#pragma unroll
            for (int i = 0; i < 8; ++i) xv[i] = Xs[k][r0 + i];  // broadcast
            float4 a = *reinterpret_cast<const float4*>(&Ps[k][pc8]);
            float4 b = *reinterpret_cast<const float4*>(&Ps[k][pc8 + 4]);
            float pv[8] = {a.x, a.y, a.z, a.w, b.x, b.y, b.z, b.w};
#pragma unroll
            for (int i = 0; i < 8; ++i)
#pragma unroll
                for (int j = 0; j < 8; ++j)
                    acc[i][j] = fmaf(xv[i], pv[j], acc[i][j]);
        }
    }

    // argmin over k of (||p_k||^2 - 2 x.p_k); first-occurrence tie-break
    float pnv[8];
#pragma unroll
    for (int j = 0; j < 8; ++j) pnv[j] = pn[pc8 + j];
#pragma unroll
    for (int i = 0; i < 8; ++i) {
        float best = fmaf(-2.f, acc[i][0], pnv[0]);
        int bidx = pc8;
#pragma unroll
        for (int j = 1; j < 8; ++j) {
            float v = fmaf(-2.f, acc[i][j], pnv[j]);
            if (v < best) { best = v; bidx = pc8 + j; }  // strict < keeps first
        }
#pragma unroll
        for (int off = 1; off < 64; off <<= 1) {
            float ov = __shfl_xor(best, off);
            int   oi = __shfl_xor(bidx, off);
            if (ov < best || (ov == best && oi < bidx)) { best = ov; bidx = oi; }
        }
        if (lane == 0) idx_s[r0 + i] = bidx;
    }
    __syncthreads();

    // gather codebook rows, write quantized_st = x + (q - x), loss partials
    float ls = 0.f;
#pragma unroll
    for (int it = 0; it < 16; ++it) {
        int q = it * 256 + tid;  // 0..4095 over 32 rows x 128 float4
        int r = q >> 7;
        int f = q & 127;
        const float4 pv = *reinterpret_cast<const float4*>(
            P + (size_t)idx_s[r] * DIM + 4 * f);
        const float4 xv = *reinterpret_cast<const float4*>(
            X + (size_t)(row0 + r) * DIM + 4 * f);
        float dx = pv.x - xv.x, dy = pv.y - xv.y, dz = pv.z - xv.z, dw = pv.w - xv.w;
        float4 ov;
        ov.x = xv.x + dx; ov.y = xv.y + dy; ov.z = xv.z + dz; ov.w = xv.w + dw;
        *reinterpret_cast<float4*>(out + (size_t)(row0 + r) * DIM + 4 * f) = ov;
        ls += dx * dx + dy * dy + dz * dz + dw * dw;
    }
    double ld = (double)ls;
#pragma unroll
    for (int off = 32; off > 0; off >>= 1) ld += __shfl_down(ld, off);
    if (lane == 0) wsum[wid] = ld;
    __syncthreads();
    if (tid == 0) atomicAdd(lsum_g, wsum[0] + wsum[1] + wsum[2] + wsum[3]);
}

// loss = (1 + 0.25) * mean((q - x)^2)   (e_latent == q_latent numerically)
__global__ void finalize_kernel(const double* __restrict__ lsum_g,
                                float* __restrict__ out_loss) {
    out_loss[0] = (float)(1.25 * lsum_g[0] / ((double)N_ROWS * (double)DIM));
}

extern "C" void kernel_launch(void* const* d_in, const int* in_sizes, int n_in,
                              void* d_out, int out_size, void* d_ws, size_t ws_size,
                              hipStream_t stream) {
    const float* X = (const float*)d_in[0];
    const float* P = (const float*)d_in[1];
    float* out = (float*)d_out;

    double* lsum = (double*)d_ws;               // 8 bytes at offset 0
    float*  pn   = (float*)d_ws + 16;           // pnorms at byte offset 64

    hipMemsetAsync(d_ws, 0, 64, stream);
    pnorm_kernel<<<KP, 64, 0, stream>>>(P, pn);
    vq_main<<<N_ROWS / BM, 256, 0, stream>>>(X, P, pn, out, lsum);
    finalize_kernel<<<1, 1, 0, stream>>>(lsum, out + (size_t)N_ROWS * DIM);
    // prototypes passthrough (output 2)
    hipMemcpyAsync(out + (size_t)N_ROWS * DIM + 1, P,
                   (size_t)KP * DIM * sizeof(float),
                   hipMemcpyDeviceToDevice, stream);
}

// Round 2
// 363.350 us; speedup vs baseline: 3.0186x; 3.0186x over previous
//
#include <hip/hip_runtime.h>

constexpr int N_ROWS = 131072;
constexpr int DIM    = 512;
constexpr int KP     = 512;
constexpr int BM     = 64;        // rows per score block
constexpr int BK     = 64;        // K chunk
constexpr int LDA    = BK + 8;    // padded bf16 per LDS row (144 B stride)

typedef float  f32x4  __attribute__((ext_vector_type(4)));
typedef short  short8 __attribute__((ext_vector_type(8)));

__device__ inline unsigned short f2bf(float f) {
    unsigned u = __builtin_bit_cast(unsigned, f);
    unsigned r = (u + 0x7FFFu + ((u >> 16) & 1u)) >> 16;
    return (unsigned short)r;
}

// ---------------------------------------------------------------------------
// prep: pn[k] = ||P[k]||^2 (fp32) and Pb = bf16(P). One wave per proto row.
// ---------------------------------------------------------------------------
__global__ void prep_kernel(const float* __restrict__ P, float* __restrict__ pn,
                            unsigned short* __restrict__ Pb) {
    const int k = blockIdx.x, lane = threadIdx.x;  // 64 lanes
    const float* row = P + (size_t)k * DIM;
    float4 a = *reinterpret_cast<const float4*>(row + lane * 8);
    float4 b = *reinterpret_cast<const float4*>(row + lane * 8 + 4);
    float s = a.x*a.x + a.y*a.y + a.z*a.z + a.w*a.w
            + b.x*b.x + b.y*b.y + b.z*b.z + b.w*b.w;
    unsigned short o[8] = {f2bf(a.x), f2bf(a.y), f2bf(a.z), f2bf(a.w),
                           f2bf(b.x), f2bf(b.y), f2bf(b.z), f2bf(b.w)};
    *reinterpret_cast<short8*>(Pb + (size_t)k * DIM + lane * 8) =
        *reinterpret_cast<const short8*>(o);
#pragma unroll
    for (int off = 32; off > 0; off >>= 1) s += __shfl_down(s, off);
    if (lane == 0) pn[k] = s;
}

// ---------------------------------------------------------------------------
// score: per block, 64 rows x all 512 protos via bf16 MFMA; fused argmin.
// 512 threads = 8 waves; wave w owns cols w*64..w*64+63 (4 col-tiles),
// all 4 row-tiles. acc[rt][ct] is one 16x16 frag (4 fp32/lane).
// A staged in LDS (fp32->bf16 on the fly, X read once from HBM);
// B frag-direct from L2-resident Pb: lane holds P[c0+ct*16+(l&15)][k0+(l>>4)*8+i].
// ---------------------------------------------------------------------------
__global__ __launch_bounds__(512)
void score_kernel(const float* __restrict__ X, const unsigned short* __restrict__ Pb,
                  const float* __restrict__ pn, int* __restrict__ idxg) {
    __shared__ __align__(16) unsigned short As[2][BM][LDA];
    __shared__ float redv[8][BM];
    __shared__ int   redi[8][BM];

    const int tid  = threadIdx.x;
    const int lane = tid & 63;
    const int wid  = tid >> 6;
    const int lr   = lane & 15;   // frag row (A) / col (B)
    const int lg   = lane >> 4;   // k-group
    const int c0   = wid * 64;
    const int row0 = blockIdx.x * BM;

    f32x4 acc[4][4];
#pragma unroll
    for (int i = 0; i < 4; ++i)
#pragma unroll
        for (int j = 0; j < 4; ++j) acc[i][j] = {0.f, 0.f, 0.f, 0.f};

    auto stage = [&](int buf, int ks) {
        const int k0 = ks * BK;
#pragma unroll
        for (int h = 0; h < 2; ++h) {
            int q = tid + h * 512;        // 0..1023 over 64 rows x 16 float4
            int r = q >> 4, f = q & 15;
            float4 v = *reinterpret_cast<const float4*>(
                X + (size_t)(row0 + r) * DIM + k0 + f * 4);
            unsigned long long pk =
                (unsigned long long)f2bf(v.x) | ((unsigned long long)f2bf(v.y) << 16) |
                ((unsigned long long)f2bf(v.z) << 32) | ((unsigned long long)f2bf(v.w) << 48);
            *reinterpret_cast<unsigned long long*>(&As[buf][r][f * 4]) = pk;
        }
    };

    int cur = 0;
    stage(0, 0);
    for (int ks = 0; ks < DIM / BK; ++ks) {
        __syncthreads();
        if (ks < DIM / BK - 1) stage(cur ^ 1, ks + 1);
        const int k0 = ks * BK;
#pragma unroll
        for (int kk = 0; kk < 2; ++kk) {
            short8 bfrag[4];
#pragma unroll
            for (int ct = 0; ct < 4; ++ct)
                bfrag[ct] = *reinterpret_cast<const short8*>(
                    Pb + (size_t)(c0 + ct * 16 + lr) * DIM + k0 + kk * 32 + lg * 8);
            short8 afrag[4];
#pragma unroll
            for (int rt = 0; rt < 4; ++rt)
                afrag[rt] = *reinterpret_cast<const short8*>(
                    &As[cur][rt * 16 + lr][kk * 32 + lg * 8]);
#pragma unroll
            for (int rt = 0; rt < 4; ++rt)
#pragma unroll
                for (int ct = 0; ct < 4; ++ct)
                    acc[rt][ct] = __builtin_amdgcn_mfma_f32_16x16x32_bf16(
                        afrag[rt], bfrag[ct], acc[rt][ct], 0, 0, 0);
        }
        cur ^= 1;
    }

    // dist = pn[c] - 2*dot; argmin with first-occurrence tie-break.
    float pnv[4];
#pragma unroll
    for (int ct = 0; ct < 4; ++ct) pnv[ct] = pn[c0 + ct * 16 + lr];
#pragma unroll
    for (int rt = 0; rt < 4; ++rt) {
#pragma unroll
        for (int j = 0; j < 4; ++j) {
            float best = fmaf(-2.f, acc[rt][0][j], pnv[0]);
            int bidx = c0 + lr;
#pragma unroll
            for (int ct = 1; ct < 4; ++ct) {
                float d = fmaf(-2.f, acc[rt][ct][j], pnv[ct]);
                int ci = c0 + ct * 16 + lr;
                if (d < best) { best = d; bidx = ci; }
            }
#pragma unroll
            for (int m = 1; m < 16; m <<= 1) {
                float ov = __shfl_xor(best, m);
                int   oi = __shfl_xor(bidx, m);
                if (ov < best || (ov == best && oi < bidx)) { best = ov; bidx = oi; }
            }
            if (lr == 0) {
                int r = rt * 16 + lg * 4 + j;   // C/D layout: row=(lane>>4)*4+j
                redv[wid][r] = best;
                redi[wid][r] = bidx;
            }
        }
    }
    __syncthreads();
    if (tid < BM) {
        float best = redv[0][tid];
        int bidx = redi[0][tid];
#pragma unroll
        for (int w = 1; w < 8; ++w) {
            float v = redv[w][tid];
            int i = redi[w][tid];
            if (v < best || (v == best && i < bidx)) { best = v; bidx = i; }
        }
        idxg[row0 + tid] = bidx;
    }
}

// ---------------------------------------------------------------------------
// out: quantized = P[idx[r]] (== x + (q-x)), loss partial sums.
// ---------------------------------------------------------------------------
__global__ __launch_bounds__(256)
void out_kernel(const float* __restrict__ X, const float* __restrict__ P,
                const int* __restrict__ idxg, float* __restrict__ out,
                double* __restrict__ lsum) {
    constexpr int NF4 = N_ROWS * (DIM / 4);
    const int stride = gridDim.x * blockDim.x;
    const int tid = threadIdx.x, lane = tid & 63, wid = tid >> 6;
    float ls = 0.f;
    for (int q = blockIdx.x * blockDim.x + tid; q < NF4; q += stride) {
        int r = q >> 7, f = q & 127;
        int k = idxg[r];
        float4 pv = *reinterpret_cast<const float4*>(P + (size_t)k * DIM + 4 * f);
        float4 xv = *reinterpret_cast<const float4*>(X + (size_t)r * DIM + 4 * f);
        *reinterpret_cast<float4*>(out + (size_t)r * DIM + 4 * f) = pv;
        float dx = pv.x - xv.x, dy = pv.y - xv.y, dz = pv.z - xv.z, dw = pv.w - xv.w;
        ls += dx * dx + dy * dy + dz * dz + dw * dw;
    }
    double ld = (double)ls;
#pragma unroll
    for (int off = 32; off > 0; off >>= 1) ld += __shfl_down(ld, off);
    __shared__ double wsum[4];
    if (lane == 0) wsum[wid] = ld;
    __syncthreads();
    if (tid == 0) atomicAdd(lsum, wsum[0] + wsum[1] + wsum[2] + wsum[3]);
}

__global__ void finalize_kernel(const double* __restrict__ lsum,
                                float* __restrict__ out_loss) {
    out_loss[0] = (float)(1.25 * lsum[0] / ((double)N_ROWS * (double)DIM));
}

extern "C" void kernel_launch(void* const* d_in, const int* in_sizes, int n_in,
                              void* d_out, int out_size, void* d_ws, size_t ws_size,
                              hipStream_t stream) {
    const float* X = (const float*)d_in[0];
    const float* P = (const float*)d_in[1];
    float* out = (float*)d_out;

    // ws layout: [0,8) lsum double; [256, 256+2K) pn; [4096, +512K) Pb bf16;
    // [528384, +512K) idx int32.  Total ~1.04 MB.
    double*          lsum = (double*)d_ws;
    float*           pn   = (float*)((char*)d_ws + 256);
    unsigned short*  Pb   = (unsigned short*)((char*)d_ws + 4096);
    int*             idxg = (int*)((char*)d_ws + 4096 + (size_t)KP * DIM * 2);

    hipMemsetAsync(d_ws, 0, 64, stream);
    prep_kernel<<<KP, 64, 0, stream>>>(P, pn, Pb);
    score_kernel<<<N_ROWS / BM, 512, 0, stream>>>(X, Pb, pn, idxg);
    out_kernel<<<2048, 256, 0, stream>>>(X, P, idxg, out, lsum);
    finalize_kernel<<<1, 1, 0, stream>>>(lsum, out + (size_t)N_ROWS * DIM);
    hipMemcpyAsync(out + (size_t)N_ROWS * DIM + 1, P,
                   (size_t)KP * DIM * sizeof(float),
                   hipMemcpyDeviceToDevice, stream);
}

// Round 4
// 312.908 us; speedup vs baseline: 3.5052x; 1.1612x over previous
//
#include <hip/hip_runtime.h>

constexpr int N_ROWS = 131072;
constexpr int DIM    = 512;
constexpr int KP     = 512;
constexpr int BM     = 64;        // rows per block
constexpr int BK     = 64;        // K chunk
constexpr int NSTEP  = DIM / BK;  // 8
constexpr int LDA    = BK + 8;    // 72 bf16 -> 144 B row stride (16B aligned)

typedef float f32x4  __attribute__((ext_vector_type(4)));
typedef short short8 __attribute__((ext_vector_type(8)));

__device__ inline unsigned short f2bf(float f) {
    unsigned u = __builtin_bit_cast(unsigned, f);
    unsigned r = (u + 0x7FFFu + ((u >> 16) & 1u)) >> 16;
    return (unsigned short)r;
}
__device__ inline unsigned pk2bf(float a, float b) {
    return (unsigned)f2bf(a) | ((unsigned)f2bf(b) << 16);
}

__device__ inline void gload_lds16(const unsigned short* g, unsigned short* l) {
    __builtin_amdgcn_global_load_lds(
        (const __attribute__((address_space(1))) unsigned*)g,
        (__attribute__((address_space(3))) unsigned*)l, 16, 0, 0);
}

// ---------------------------------------------------------------------------
// prep: pn[k] = ||P[k]||^2 (fp32); PbSwz = bf16(P) in the XOR-swizzled,
// step-blocked layout score_fused stages linearly via global_load_lds.
// Unit (16B = 8 bf16) at [ks*4096 + c*8 + (k8 ^ (c&7))] holds P[c][ks*64+k8*8 ..+8].
// ---------------------------------------------------------------------------
__global__ void prep_kernel(const float* __restrict__ P, float* __restrict__ pn,
                            unsigned short* __restrict__ PbSwz) {
    const int c = blockIdx.x, l = threadIdx.x;  // 64 lanes
    const float* row = P + (size_t)c * DIM;
    float4 a = *reinterpret_cast<const float4*>(row + l * 8);
    float4 b = *reinterpret_cast<const float4*>(row + l * 8 + 4);
    float s = a.x*a.x + a.y*a.y + a.z*a.z + a.w*a.w
            + b.x*b.x + b.y*b.y + b.z*b.z + b.w*b.w;
    uint4 pk;
    pk.x = pk2bf(a.x, a.y); pk.y = pk2bf(a.z, a.w);
    pk.z = pk2bf(b.x, b.y); pk.w = pk2bf(b.z, b.w);
    const int ks = l >> 3, k8 = l & 7;
    const size_t unit = (size_t)ks * (KP * 8) + c * 8 + (k8 ^ (c & 7));
    *reinterpret_cast<uint4*>(PbSwz + unit * 8) = pk;
#pragma unroll
    for (int off = 32; off > 0; off >>= 1) s += __shfl_down(s, off);
    if (l == 0) pn[c] = s;
}

// ---------------------------------------------------------------------------
// Fused: bf16-MFMA scores (64 rows x 512 protos), argmin, analytic loss,
// codebook gather + quantized write. 512 threads = 8 waves; wave w owns
// col-group w*64 (4 col-tiles), all 4 row-tiles.
// ---------------------------------------------------------------------------
__global__ __launch_bounds__(512, 4)
void score_fused(const float* __restrict__ X, const float* __restrict__ P,
                 const unsigned short* __restrict__ Pb,
                 const float* __restrict__ pn,
                 float* __restrict__ out, double* __restrict__ lsum) {
    __shared__ __align__(16) unsigned short Bs[KP * BK];   // 64 KB, swizzled
    __shared__ __align__(16) unsigned short As[BM][LDA];   // 9 KB, padded
    __shared__ float redv[8][BM];
    __shared__ int   redi[8][BM];
    __shared__ int   idx_s[BM];
    __shared__ float xs_w[8];

    const int tid  = threadIdx.x;
    const int lane = tid & 63;
    const int wid  = tid >> 6;
    const int lr   = tid & 15;
    const int lg   = (tid >> 4) & 3;
    const int c0   = wid * 64;
    const size_t row0 = (size_t)blockIdx.x * BM;

    const int ar = tid >> 3, aj = tid & 7;   // A staging: row, octet-of-8-floats
    const float* aptr = X + (row0 + ar) * DIM + aj * 8;

    f32x4 acc[4][4];
#pragma unroll
    for (int i = 0; i < 4; ++i)
#pragma unroll
        for (int j = 0; j < 4; ++j) acc[i][j] = {0.f, 0.f, 0.f, 0.f};
    float xsq = 0.f;

    float4 xv0 = *reinterpret_cast<const float4*>(aptr);
    float4 xv1 = *reinterpret_cast<const float4*>(aptr + 4);

    for (int ks = 0; ks < NSTEP; ++ks) {
        __syncthreads();   // previous step's compute done; LDS safe to overwrite
        // B: direct global->LDS linear copy (source pre-swizzled by prep)
        {
            const unsigned short* src = Pb + ((size_t)ks * 4096 + wid * 512 + lane) * 8;
            unsigned short* dst = Bs + (size_t)wid * 4096;
#pragma unroll
            for (int j = 0; j < 8; ++j)
                gload_lds16(src + j * 512, dst + j * 512);
        }
        // A: convert prefetched regs, ds_write; accumulate ||x||^2 in fp32
        {
            uint4 w;
            w.x = pk2bf(xv0.x, xv0.y); w.y = pk2bf(xv0.z, xv0.w);
            w.z = pk2bf(xv1.x, xv1.y); w.w = pk2bf(xv1.z, xv1.w);
            *reinterpret_cast<uint4*>(&As[ar][aj * 8]) = w;
            xsq += xv0.x*xv0.x + xv0.y*xv0.y + xv0.z*xv0.z + xv0.w*xv0.w
                 + xv1.x*xv1.x + xv1.y*xv1.y + xv1.z*xv1.z + xv1.w*xv1.w;
        }
        __syncthreads();   // drains vmcnt/lgkm -> B and A landed in LDS
        if (ks + 1 < NSTEP) {   // prefetch next A chunk; latency hides under MFMA
            xv0 = *reinterpret_cast<const float4*>(aptr + (ks + 1) * BK);
            xv1 = *reinterpret_cast<const float4*>(aptr + (ks + 1) * BK + 4);
        }
#pragma unroll
        for (int kk = 0; kk < 2; ++kk) {
            short8 a[4];
#pragma unroll
            for (int rt = 0; rt < 4; ++rt)
                a[rt] = *reinterpret_cast<const short8*>(
                    &As[rt * 16 + lr][kk * 32 + lg * 8]);
#pragma unroll
            for (int ct = 0; ct < 4; ++ct) {
                const int c = c0 + ct * 16 + lr;
                const int u = c * 8 + ((kk * 4 + lg) ^ (c & 7));  // un-swizzle
                short8 b = *reinterpret_cast<const short8*>(&Bs[u * 8]);
#pragma unroll
                for (int rt = 0; rt < 4; ++rt)
                    acc[rt][ct] = __builtin_amdgcn_mfma_f32_16x16x32_bf16(
                        a[rt], b, acc[rt][ct], 0, 0, 0);
            }
        }
    }

    // ||x||^2 wave-reduce
    float xs = xsq;
#pragma unroll
    for (int off = 32; off > 0; off >>= 1) xs += __shfl_down(xs, off);
    if (lane == 0) xs_w[wid] = xs;

    // argmin: dist = pn[c] - 2*dot; first-occurrence tie-break
    float pnv[4];
#pragma unroll
    for (int ct = 0; ct < 4; ++ct) pnv[ct] = pn[c0 + ct * 16 + lr];
#pragma unroll
    for (int rt = 0; rt < 4; ++rt) {
#pragma unroll
        for (int j = 0; j < 4; ++j) {
            float best = fmaf(-2.f, acc[rt][0][j], pnv[0]);
            int bidx = c0 + lr;
#pragma unroll
            for (int ct = 1; ct < 4; ++ct) {
                float d = fmaf(-2.f, acc[rt][ct][j], pnv[ct]);
                int ci = c0 + ct * 16 + lr;
                if (d < best) { best = d; bidx = ci; }
            }
#pragma unroll
            for (int m = 1; m < 16; m <<= 1) {
                float ov = __shfl_xor(best, m);
                int   oi = __shfl_xor(bidx, m);
                if (ov < best || (ov == best && oi < bidx)) { best = ov; bidx = oi; }
            }
            if (lr == 0) {
                int r = rt * 16 + lg * 4 + j;   // C/D: row=(lane>>4)*4+reg
                redv[wid][r] = best;
                redi[wid][r] = bidx;
            }
        }
    }
    __syncthreads();

    double contrib = 0.0;
    if (tid < BM) {
        float best = redv[0][tid];
        int bidx = redi[0][tid];
#pragma unroll
        for (int w = 1; w < 8; ++w) {
            float v = redv[w][tid];
            int i = redi[w][tid];
            if (v < best || (v == best && i < bidx)) { best = v; bidx = i; }
        }
        idx_s[tid] = bidx;
        contrib = (double)best;   // = ||p_b||^2 - 2 x.p_b  for this row
    }
    if (wid == 0) {
#pragma unroll
        for (int off = 32; off > 0; off >>= 1) contrib += __shfl_down(contrib, off);
        if (tid == 0) {
            double tot = contrib;
#pragma unroll
            for (int w = 0; w < 8; ++w) tot += (double)xs_w[w];
            atomicAdd(lsum, tot);   // Σ ||q-x||^2 for this block
        }
    }
    __syncthreads();

    // gather fp32 codebook rows (L2-resident) + write quantized
#pragma unroll
    for (int it = 0; it < 16; ++it) {
        int q = it * 512 + tid;
        int r = q >> 7, f = q & 127;
        float4 pv = *reinterpret_cast<const float4*>(
            P + (size_t)idx_s[r] * DIM + f * 4);
        *reinterpret_cast<float4*>(out + (row0 + r) * DIM + f * 4) = pv;
    }
}

__global__ void finalize_kernel(const double* __restrict__ lsum,
                                float* __restrict__ out_loss) {
    out_loss[0] = (float)(1.25 * lsum[0] / ((double)N_ROWS * (double)DIM));
}

extern "C" void kernel_launch(void* const* d_in, const int* in_sizes, int n_in,
                              void* d_out, int out_size, void* d_ws, size_t ws_size,
                              hipStream_t stream) {
    const float* X = (const float*)d_in[0];
    const float* P = (const float*)d_in[1];
    float* out = (float*)d_out;

    // ws: [0,8) lsum; [256,+2K) pn; [4096,+512K) PbSwz
    double*         lsum  = (double*)d_ws;
    float*          pn    = (float*)((char*)d_ws + 256);
    unsigned short* PbSwz = (unsigned short*)((char*)d_ws + 4096);

    (void)hipMemsetAsync(d_ws, 0, 64, stream);
    prep_kernel<<<KP, 64, 0, stream>>>(P, pn, PbSwz);
    score_fused<<<N_ROWS / BM, 512, 0, stream>>>(X, P, PbSwz, pn, out, lsum);
    finalize_kernel<<<1, 1, 0, stream>>>(lsum, out + (size_t)N_ROWS * DIM);
    (void)hipMemcpyAsync(out + (size_t)N_ROWS * DIM + 1, P,
                         (size_t)KP * DIM * sizeof(float),
                         hipMemcpyDeviceToDevice, stream);
}

// Round 5
// 294.357 us; speedup vs baseline: 3.7262x; 1.0630x over previous
//
#include <hip/hip_runtime.h>

constexpr int N_ROWS = 131072;
constexpr int DIM    = 512;
constexpr int KP     = 512;
constexpr int BM     = 128;       // rows per score block
constexpr int BN     = 128;       // cols per score block (one panel)
constexpr int BK     = 64;        // K chunk
constexpr int NSTEP  = DIM / BK;  // 8
constexpr int NPB    = KP / BN;   // 4 panels
constexpr int LDA    = BK + 8;    // 72 shorts -> 144 B row stride

typedef float f32x4  __attribute__((ext_vector_type(4)));
typedef short short8 __attribute__((ext_vector_type(8)));

__device__ inline unsigned short f2bf(float f) {
    unsigned u = __builtin_bit_cast(unsigned, f);
    unsigned r = (u + 0x7FFFu + ((u >> 16) & 1u)) >> 16;
    return (unsigned short)r;
}
__device__ inline unsigned pk2bf(float a, float b) {
    return (unsigned)f2bf(a) | ((unsigned)f2bf(b) << 16);
}
// monotone float<->uint (total order preserved under unsigned compare)
__device__ inline unsigned mono(float f) {
    unsigned u = __builtin_bit_cast(unsigned, f);
    return (u >> 31) ? ~u : (u | 0x80000000u);
}
__device__ inline float unmono(unsigned m) {
    unsigned u = (m & 0x80000000u) ? (m & 0x7FFFFFFFu) : ~m;
    return __builtin_bit_cast(float, u);
}
__device__ inline void gload_lds16(const unsigned short* g, unsigned short* l) {
    __builtin_amdgcn_global_load_lds(
        (const __attribute__((address_space(1))) unsigned*)g,
        (__attribute__((address_space(3))) unsigned*)l, 16, 0, 0);
}

// ---------------------------------------------------------------------------
// prep: pn[c] = ||P[c]||^2; PbSwz = bf16(P) in panel/step-blocked, XOR-swizzled
// layout. 16B unit index: pb*8192 + ks*1024 + cl*8 + (k8 ^ (cl&7)),
// holding P[c][ks*64 + k8*8 .. +8], pb=c>>7, cl=c&127.
// ---------------------------------------------------------------------------
__global__ void prep_kernel(const float* __restrict__ P, float* __restrict__ pn,
                            unsigned short* __restrict__ PbSwz) {
    const int c = blockIdx.x, l = threadIdx.x;  // 64 lanes
    const float* row = P + (size_t)c * DIM;
    float4 a = *reinterpret_cast<const float4*>(row + l * 8);
    float4 b = *reinterpret_cast<const float4*>(row + l * 8 + 4);
    float s = a.x*a.x + a.y*a.y + a.z*a.z + a.w*a.w
            + b.x*b.x + b.y*b.y + b.z*b.z + b.w*b.w;
    uint4 pk;
    pk.x = pk2bf(a.x, a.y); pk.y = pk2bf(a.z, a.w);
    pk.z = pk2bf(b.x, b.y); pk.w = pk2bf(b.z, b.w);
    const int ks = l >> 3, k8 = l & 7;
    const int pb = c >> 7, cl = c & 127;
    const size_t unit = (size_t)pb * 8192 + ks * 1024 + cl * 8 + (k8 ^ (cl & 7));
    *reinterpret_cast<uint4*>(PbSwz + unit * 8) = pk;
#pragma unroll
    for (int off = 32; off > 0; off >>= 1) s += __shfl_down(s, off);
    if (l == 0) pn[c] = s;
}

// ---------------------------------------------------------------------------
// score: m97-shaped 128x128 tile, 4 waves (2 row-groups x 2 col-groups),
// BK=64 single-buffered. Emits per-row packed argmin keys via atomicMin(u64);
// panel-0 blocks also accumulate sum(||x||^2) into lsum.
// ---------------------------------------------------------------------------
__global__ __launch_bounds__(256)
void score_kernel(const float* __restrict__ X, const unsigned short* __restrict__ Pb,
                  const float* __restrict__ pn,
                  unsigned long long* __restrict__ keys,
                  double* __restrict__ lsum) {
    __shared__ __align__(16) unsigned short Bs[BN * BK];   // 16 KB swizzled
    __shared__ __align__(16) unsigned short As[BM][LDA];   // 18 KB padded
    __shared__ float redv[4][64];
    __shared__ int   redi[4][64];
    __shared__ float xs_s[4];

    const int tid  = threadIdx.x;
    const int lane = tid & 63;
    const int wid  = tid >> 6;      // 0..3
    const int rw   = wid >> 1;      // row-group 0..1 (64 rows each)
    const int cw   = wid & 1;       // col-group 0..1 (64 cols each)
    const int lr   = tid & 15;
    const int lg   = (tid >> 4) & 3;
    const int pb   = blockIdx.x & 3;
    const size_t row0 = (size_t)(blockIdx.x >> 2) * BM;
    const int c0   = pb * BN + cw * 64;

    const int ar = tid >> 1, ah = tid & 1;   // A-stage: row, 32-float half
    const float* aX = X + (row0 + ar) * DIM + ah * 32;

    f32x4 acc[4][4];
#pragma unroll
    for (int i = 0; i < 4; ++i)
#pragma unroll
        for (int j = 0; j < 4; ++j) acc[i][j] = {0.f, 0.f, 0.f, 0.f};
    float xsq = 0.f;

    for (int ks = 0; ks < NSTEP; ++ks) {
        __syncthreads();
        // B: 16 KB global->LDS (source pre-swizzled; dest linear)
        {
            const unsigned short* src =
                Pb + ((size_t)pb * 8192 + ks * 1024 + wid * 256 + lane) * 8;
            unsigned short* dst = Bs + (size_t)wid * 256 * 8;
#pragma unroll
            for (int j = 0; j < 4; ++j)
                gload_lds16(src + j * 64 * 8, dst + j * 64 * 8);
        }
        // A: 32 fp32 per thread -> bf16 -> LDS
        {
            float4 v[8];
#pragma unroll
            for (int i = 0; i < 8; ++i)
                v[i] = *reinterpret_cast<const float4*>(aX + ks * BK + i * 4);
            unsigned short* ad = &As[ar][ah * 32];
#pragma unroll
            for (int i = 0; i < 4; ++i) {
                uint4 w;
                w.x = pk2bf(v[2*i].x, v[2*i].y);
                w.y = pk2bf(v[2*i].z, v[2*i].w);
                w.z = pk2bf(v[2*i+1].x, v[2*i+1].y);
                w.w = pk2bf(v[2*i+1].z, v[2*i+1].w);
                *reinterpret_cast<uint4*>(ad + i * 8) = w;
            }
            if (pb == 0) {
#pragma unroll
                for (int i = 0; i < 8; ++i)
                    xsq += v[i].x*v[i].x + v[i].y*v[i].y
                         + v[i].z*v[i].z + v[i].w*v[i].w;
            }
        }
        __syncthreads();
#pragma unroll
        for (int kk = 0; kk < 2; ++kk) {
            short8 a[4];
#pragma unroll
            for (int rt = 0; rt < 4; ++rt)
                a[rt] = *reinterpret_cast<const short8*>(
                    &As[rw * 64 + rt * 16 + lr][kk * 32 + lg * 8]);
#pragma unroll
            for (int ct = 0; ct < 4; ++ct) {
                const int cl = cw * 64 + ct * 16 + lr;
                const int u  = cl * 8 + ((kk * 4 + lg) ^ (cl & 7));
                short8 b = *reinterpret_cast<const short8*>(&Bs[u * 8]);
#pragma unroll
                for (int rt = 0; rt < 4; ++rt)
                    acc[rt][ct] = __builtin_amdgcn_mfma_f32_16x16x32_bf16(
                        a[rt], b, acc[rt][ct], 0, 0, 0);
            }
        }
    }

    // sum ||x||^2 (panel-0 blocks only)
    if (pb == 0) {
        float xs = xsq;
#pragma unroll
        for (int off = 32; off > 0; off >>= 1) xs += __shfl_down(xs, off);
        if (lane == 0) xs_s[wid] = xs;
    }

    // per-wave argmin over its 64 cols; dist = pn[c] - 2*dot
    float pnv[4];
#pragma unroll
    for (int ct = 0; ct < 4; ++ct) pnv[ct] = pn[c0 + ct * 16 + lr];
#pragma unroll
    for (int rt = 0; rt < 4; ++rt) {
#pragma unroll
        for (int j = 0; j < 4; ++j) {
            float best = fmaf(-2.f, acc[rt][0][j], pnv[0]);
            int bidx = c0 + lr;
#pragma unroll
            for (int ct = 1; ct < 4; ++ct) {
                float d = fmaf(-2.f, acc[rt][ct][j], pnv[ct]);
                int ci = c0 + ct * 16 + lr;
                if (d < best) { best = d; bidx = ci; }
            }
#pragma unroll
            for (int m = 1; m < 16; m <<= 1) {
                float ov = __shfl_xor(best, m);
                int   oi = __shfl_xor(bidx, m);
                if (ov < best || (ov == best && oi < bidx)) { best = ov; bidx = oi; }
            }
            if (lr == 0) {
                int r = rt * 16 + lg * 4 + j;   // C/D: row=(lane>>4)*4+reg
                redv[wid][r] = best;
                redi[wid][r] = bidx;
            }
        }
    }
    __syncthreads();

    // combine col-groups, pack, atomicMin into global keys
    if (tid < 128) {
        const int rg = tid >> 6, r = tid & 63;
        float v0 = redv[rg * 2][r];     int i0 = redi[rg * 2][r];
        float v1 = redv[rg * 2 + 1][r]; int i1 = redi[rg * 2 + 1][r];
        if (v1 < v0) { v0 = v1; i0 = i1; }   // tie -> cw0 (lower idx)
        unsigned long long key =
            ((unsigned long long)mono(v0) << 32) | (unsigned)i0;
        atomicMin(&keys[row0 + rg * 64 + r], key);
    }
    if (pb == 0 && tid == 0)
        atomicAdd(lsum, (double)xs_s[0] + (double)xs_s[1]
                      + (double)xs_s[2] + (double)xs_s[3]);
}

// ---------------------------------------------------------------------------
// gather: out[r] = P[idx[r]]; loss += best-dist per row (decoded from key).
// ---------------------------------------------------------------------------
__global__ __launch_bounds__(256)
void gather_kernel(const float* __restrict__ P,
                   const unsigned long long* __restrict__ keys,
                   float* __restrict__ out, double* __restrict__ lsum) {
    constexpr int NQ = N_ROWS * (DIM / 4);
    const int stride = gridDim.x * blockDim.x;
    const int tid = threadIdx.x, lane = tid & 63, wid = tid >> 6;
    double ls = 0.0;
    for (int q = blockIdx.x * blockDim.x + tid; q < NQ; q += stride) {
        int r = q >> 7, f = q & 127;
        unsigned long long key = keys[r];
        int idx = (int)(key & 0xFFFFFFFFu);
        float4 pv = *reinterpret_cast<const float4*>(
            P + (size_t)idx * DIM + 4 * f);
        *reinterpret_cast<float4*>(out + (size_t)r * DIM + 4 * f) = pv;
        if (f == 0) ls += (double)unmono((unsigned)(key >> 32));
    }
#pragma unroll
    for (int off = 32; off > 0; off >>= 1) ls += __shfl_down(ls, off);
    __shared__ double wsum[4];
    if (lane == 0) wsum[wid] = ls;
    __syncthreads();
    if (tid == 0) atomicAdd(lsum, wsum[0] + wsum[1] + wsum[2] + wsum[3]);
}

__global__ void finalize_kernel(const double* __restrict__ lsum,
                                float* __restrict__ out_loss) {
    out_loss[0] = (float)(1.25 * lsum[0] / ((double)N_ROWS * (double)DIM));
}

extern "C" void kernel_launch(void* const* d_in, const int* in_sizes, int n_in,
                              void* d_out, int out_size, void* d_ws, size_t ws_size,
                              hipStream_t stream) {
    const float* X = (const float*)d_in[0];
    const float* P = (const float*)d_in[1];
    float* out = (float*)d_out;

    // ws: [0,8) lsum; [256,+2K) pn; [4096,+512K) PbSwz; [528384,+1M) keys
    double*             lsum  = (double*)d_ws;
    float*              pn    = (float*)((char*)d_ws + 256);
    unsigned short*     PbSwz = (unsigned short*)((char*)d_ws + 4096);
    unsigned long long* keys  = (unsigned long long*)((char*)d_ws + 4096 + 524288);

    (void)hipMemsetAsync(d_ws, 0, 64, stream);
    (void)hipMemsetAsync(keys, 0xFF, (size_t)N_ROWS * 8, stream);
    prep_kernel<<<KP, 64, 0, stream>>>(P, pn, PbSwz);
    score_kernel<<<(N_ROWS / BM) * NPB, 256, 0, stream>>>(X, PbSwz, pn, keys, lsum);
    gather_kernel<<<4096, 256, 0, stream>>>(P, keys, out, lsum);
    finalize_kernel<<<1, 1, 0, stream>>>(lsum, out + (size_t)N_ROWS * DIM);
    (void)hipMemcpyAsync(out + (size_t)N_ROWS * DIM + 1, P,
                         (size_t)KP * DIM * sizeof(float),
                         hipMemcpyDeviceToDevice, stream);
}

// Round 6
// 269.362 us; speedup vs baseline: 4.0719x; 1.0928x over previous
//
#include <hip/hip_runtime.h>

constexpr int N_ROWS = 131072;
constexpr int DIM    = 512;
constexpr int KP     = 512;
constexpr int BM     = 64;         // rows per block
constexpr int PBC    = 128;        // panel cols
constexpr int BKS    = 32;         // K per B-stage
constexpr int NPB    = KP / PBC;   // 4 panels (in-block loop)
constexpr int NKS    = DIM / BKS;  // 16 K-steps per panel

typedef float f32x4  __attribute__((ext_vector_type(4)));
typedef short short8 __attribute__((ext_vector_type(8)));

__device__ inline unsigned short f2bf(float f) {
    unsigned u = __builtin_bit_cast(unsigned, f);
    unsigned r = (u + 0x7FFFu + ((u >> 16) & 1u)) >> 16;
    return (unsigned short)r;
}
__device__ inline unsigned pk2bf(float a, float b) {
    return (unsigned)f2bf(a) | ((unsigned)f2bf(b) << 16);
}
__device__ inline void gload_lds16(const unsigned short* g, unsigned short* l) {
    // LDS dest must be WAVE-UNIFORM; HW adds lane*16.
    __builtin_amdgcn_global_load_lds(
        (const __attribute__((address_space(1))) unsigned*)g,
        (__attribute__((address_space(3))) unsigned*)l, 16, 0, 0);
}

// ---------------------------------------------------------------------------
// prep: pn[c] = ||P[c]||^2; PbSwz = bf16(P), step-blocked + XOR-swizzled:
// 16B unit for (c, k-unit ku=k/8) lives at
//   ((pb*16 + ks)*512 + cl*4 + ((ku&3) ^ (cl&3)))   where pb=c>>7, cl=c&127,
//   ks = ku>>2  (32-K-wide stages).
// ---------------------------------------------------------------------------
__global__ void prep_kernel(const float* __restrict__ P, float* __restrict__ pn,
                            unsigned short* __restrict__ PbSwz) {
    const int c = blockIdx.x, l = threadIdx.x;   // l = k-unit 0..63
    const float* row = P + (size_t)c * DIM;
    float4 a = *reinterpret_cast<const float4*>(row + l * 8);
    float4 b = *reinterpret_cast<const float4*>(row + l * 8 + 4);
    float s = a.x*a.x + a.y*a.y + a.z*a.z + a.w*a.w
            + b.x*b.x + b.y*b.y + b.z*b.z + b.w*b.w;
    uint4 pk;
    pk.x = pk2bf(a.x, a.y); pk.y = pk2bf(a.z, a.w);
    pk.z = pk2bf(b.x, b.y); pk.w = pk2bf(b.z, b.w);
    const int ks = l >> 2, k4 = l & 3;
    const int pb = c >> 7, cl = c & 127;
    const size_t unit = (size_t)(pb * 16 + ks) * 512 + cl * 4 + (k4 ^ (cl & 3));
    *reinterpret_cast<uint4*>(PbSwz + unit * 8) = pk;
#pragma unroll
    for (int off = 32; off > 0; off >>= 1) s += __shfl_down(s, off);
    if (l == 0) pn[c] = s;
}

// ---------------------------------------------------------------------------
// Fully fused: conv X->bf16 A-LDS (persistent, swizzled), 4 panels x 16 steps
// of B-staged MFMA, in-register argmin fold, analytic loss, direct out-write.
// 256 threads = 4 waves; wave w owns cols w*32..w*32+31 of current panel,
// all 64 rows (acc 4rt x 2ct).
// ---------------------------------------------------------------------------
__global__ __launch_bounds__(256, 2)
void vq_fused(const float* __restrict__ X, const float* __restrict__ P,
              const unsigned short* __restrict__ Pb, const float* __restrict__ pn,
              float* __restrict__ out, double* __restrict__ lsum) {
    __shared__ __align__(16) unsigned short As[BM * DIM];    // 64 KB swizzled
    __shared__ __align__(16) unsigned short Bs[PBC * BKS];   // 8 KB swizzled
    __shared__ float redv[4][BM];
    __shared__ int   redi[4][BM];
    __shared__ float xs_w[4];
    __shared__ int   idx_s[BM];

    const int tid  = threadIdx.x;
    const int lane = tid & 63;
    const int wid  = tid >> 6;
    const int lr   = lane & 15;
    const int lg   = lane >> 4;
    const size_t row0 = (size_t)blockIdx.x * BM;

    // ---- Phase 1: X tile -> bf16 -> swizzled A-LDS; accumulate ||x||^2 ----
    float xsq = 0.f;
#pragma unroll 8
    for (int i = 0; i < 32; ++i) {
        int q = tid + i * 256;            // 0..8191 over 64 rows x 128 float4
        int r = q >> 7, f4 = q & 127;
        float4 v = *reinterpret_cast<const float4*>(
            X + (row0 + r) * DIM + f4 * 4);
        xsq += v.x*v.x + v.y*v.y + v.z*v.z + v.w*v.w;
        unsigned long long pk =
            (unsigned long long)pk2bf(v.x, v.y) |
            ((unsigned long long)pk2bf(v.z, v.w) << 32);
        int u16 = f4 >> 1, half = f4 & 1;
        *reinterpret_cast<unsigned long long*>(
            (char*)As + r * 1024 + ((u16 ^ (r & 7)) * 16) + half * 8) = pk;
    }
    {
        float xs = xsq;
#pragma unroll
        for (int off = 32; off > 0; off >>= 1) xs += __shfl_down(xs, off);
        if (lane == 0) xs_w[wid] = xs;
    }

    // preload pn for all panels (this wave's cols)
    float pnv[NPB][2];
#pragma unroll
    for (int pb = 0; pb < NPB; ++pb)
#pragma unroll
        for (int ct = 0; ct < 2; ++ct)
            pnv[pb][ct] = pn[pb * PBC + wid * 32 + ct * 16 + lr];

    float bestv[4][4];
    int   besti[4][4];
#pragma unroll
    for (int rt = 0; rt < 4; ++rt)
#pragma unroll
        for (int j = 0; j < 4; ++j) { bestv[rt][j] = 3.4e38f; besti[rt][j] = 0; }

    __syncthreads();   // As + xs_w ready

    // ---- Phase 2: panels x K-steps ----
    for (int pb = 0; pb < NPB; ++pb) {
        f32x4 acc[4][2];
#pragma unroll
        for (int rt = 0; rt < 4; ++rt)
#pragma unroll
            for (int ct = 0; ct < 2; ++ct) acc[rt][ct] = {0.f, 0.f, 0.f, 0.f};

        for (int ks = 0; ks < NKS; ++ks) {
            if (pb | ks) __syncthreads();   // prior MFMA done; Bs reusable
            // stage B chunk: 512 units / 256 thr = 2 per thread (lane-linear)
            {
                const unsigned short* src =
                    Pb + ((size_t)(pb * 16 + ks) * 512 + wid * 128 + lane) * 8;
                unsigned short* dstu = Bs + (size_t)(wid * 128) * 8;  // uniform
                gload_lds16(src, dstu);
                gload_lds16(src + 64 * 8, dstu + 64 * 8);
            }
            __syncthreads();                // drain: Bs landed
            short8 a[4], b[2];
#pragma unroll
            for (int rt = 0; rt < 4; ++rt)
                a[rt] = *reinterpret_cast<const short8*>(
                    (char*)As + (rt * 16 + lr) * 1024 +
                    (((ks * 4 + lg) ^ (lr & 7)) * 16));
#pragma unroll
            for (int ct = 0; ct < 2; ++ct) {
                int cl = wid * 32 + ct * 16 + lr;
                b[ct] = *reinterpret_cast<const short8*>(
                    (char*)Bs + cl * 64 + ((lg ^ (cl & 3)) * 16));
            }
#pragma unroll
            for (int rt = 0; rt < 4; ++rt)
#pragma unroll
                for (int ct = 0; ct < 2; ++ct)
                    acc[rt][ct] = __builtin_amdgcn_mfma_f32_16x16x32_bf16(
                        a[rt], b[ct], acc[rt][ct], 0, 0, 0);
        }
        // fold this panel into running best (ascending col order; strict <)
#pragma unroll
        for (int rt = 0; rt < 4; ++rt)
#pragma unroll
            for (int j = 0; j < 4; ++j) {
                float d0 = fmaf(-2.f, acc[rt][0][j], pnv[pb][0]);
                int   i0 = pb * PBC + wid * 32 + lr;
                float d1 = fmaf(-2.f, acc[rt][1][j], pnv[pb][1]);
                if (d1 < d0) { d0 = d1; i0 += 16; }
                if (d0 < bestv[rt][j]) { bestv[rt][j] = d0; besti[rt][j] = i0; }
            }
    }

    // ---- Phase 3: argmin merge + loss + out-write ----
#pragma unroll
    for (int rt = 0; rt < 4; ++rt)
#pragma unroll
        for (int j = 0; j < 4; ++j) {
            float v = bestv[rt][j]; int bi = besti[rt][j];
#pragma unroll
            for (int m = 1; m < 16; m <<= 1) {
                float ov = __shfl_xor(v, m);
                int   oi = __shfl_xor(bi, m);
                if (ov < v || (ov == v && oi < bi)) { v = ov; bi = oi; }
            }
            if (lr == 0) {
                int r = rt * 16 + lg * 4 + j;    // C/D: row=(lane>>4)*4+reg
                redv[wid][r] = v;
                redi[wid][r] = bi;
            }
        }
    __syncthreads();

    if (wid == 0) {   // tid 0..63: one lane per row
        float v = redv[0][tid]; int bi = redi[0][tid];
#pragma unroll
        for (int w = 1; w < 4; ++w) {
            float ov = redv[w][tid]; int oi = redi[w][tid];
            if (ov < v || (ov == v && oi < bi)) { v = ov; bi = oi; }
        }
        idx_s[tid] = bi;
        double ls = (double)v;   // = ||p_b||^2 - 2 x.p_b for this row
#pragma unroll
        for (int off = 32; off > 0; off >>= 1) ls += __shfl_down(ls, off);
        if (tid == 0) {
            ls += (double)xs_w[0] + (double)xs_w[1]
                + (double)xs_w[2] + (double)xs_w[3];
            atomicAdd(lsum, ls);   // Σ ||q-x||^2 for this block
        }
    }
    __syncthreads();

#pragma unroll 4
    for (int i = 0; i < 32; ++i) {
        int q = tid + i * 256;
        int r = q >> 7, f4 = q & 127;
        float4 pv = *reinterpret_cast<const float4*>(
            P + (size_t)idx_s[r] * DIM + f4 * 4);
        *reinterpret_cast<float4*>(out + (row0 + r) * DIM + f4 * 4) = pv;
    }
}

__global__ void finalize_kernel(const double* __restrict__ lsum,
                                float* __restrict__ out_loss) {
    out_loss[0] = (float)(1.25 * lsum[0] / ((double)N_ROWS * (double)DIM));
}

extern "C" void kernel_launch(void* const* d_in, const int* in_sizes, int n_in,
                              void* d_out, int out_size, void* d_ws, size_t ws_size,
                              hipStream_t stream) {
    const float* X = (const float*)d_in[0];
    const float* P = (const float*)d_in[1];
    float* out = (float*)d_out;

    // ws: [0,8) lsum; [256,+2K) pn; [4096,+512K) PbSwz
    double*         lsum  = (double*)d_ws;
    float*          pn    = (float*)((char*)d_ws + 256);
    unsigned short* PbSwz = (unsigned short*)((char*)d_ws + 4096);

    (void)hipMemsetAsync(d_ws, 0, 64, stream);
    prep_kernel<<<KP, 64, 0, stream>>>(P, pn, PbSwz);
    vq_fused<<<N_ROWS / BM, 256, 0, stream>>>(X, P, PbSwz, pn, out, lsum);
    finalize_kernel<<<1, 1, 0, stream>>>(lsum, out + (size_t)N_ROWS * DIM);
    (void)hipMemcpyAsync(out + (size_t)N_ROWS * DIM + 1, P,
                         (size_t)KP * DIM * sizeof(float),
                         hipMemcpyDeviceToDevice, stream);
}